// Round 11
// baseline (85.498 us; speedup 1.0000x reference)
//
#include <hip/hip_runtime.h>
#include <hip/hip_fp16.h>

typedef __bf16 bf16x8 __attribute__((ext_vector_type(8)));
typedef float floatx16 __attribute__((ext_vector_type(16)));
typedef unsigned int uint;
typedef unsigned short ushort;
typedef uint  uintx4  __attribute__((ext_vector_type(4)));
typedef float floatx4 __attribute__((ext_vector_type(4)));

constexpr int Mdim = 256, Ndim = 8192, Kdim = 8192;
constexpr int BN = 64, KSPLIT = 4;
constexpr int KS = Kdim / KSPLIT;    // 2048 k per block
constexpr int NT = KS / 64;          // 32 64k-steps, 4 per superstep
constexpr int KB = Kdim / 256;       // 32 superblocks per weight row
constexpr int ROWI = 148;            // 37 chunks x 16B = 592B padded row slot
constexpr int SLOTI = 64 * ROWI;     // 9472 ints = 37888 B per superblock slot

union U8 { uint u[4]; bf16x8 v; };

__device__ __forceinline__ uint cvtpk(float lo, float hi) {
  uint r; asm("v_cvt_pk_bf16_f32 %0, %1, %2" : "=v"(r) : "v"(lo), "v"(hi));
  return r;
}
template <typename T>
__device__ __forceinline__ T gld(const void* p) {
  return *(const __attribute__((address_space(1))) T*)p;
}
__device__ __forceinline__ void glds16(const void* g, void* l) {
  __builtin_amdgcn_global_load_lds(
      (const __attribute__((address_space(1))) uint*)g,
      (__attribute__((address_space(3))) uint*)l, 16, 0, 0);
}
#define WAITVM(n) asm volatile("s_waitcnt vmcnt(" #n ")" ::: "memory")

template<bool PRE>
__global__ __launch_bounds__(256, 2)
void q4k_gemm(const float* __restrict__ x, const bf16x8* __restrict__ xbf,
              const int* __restrict__ qw, const float* __restrict__ bias,
              float* __restrict__ out)
{
  // two superblock slots: [row 0..63][chunk 0..36] chunks: 0-3 meta, 4-35 qs
  // (XOR-permuted within 128B groups), 36 pad. 75776 B total.
  __shared__ __align__(16) int Qs[2 * SLOTI];

  const int tid = threadIdx.x;
  const int bid = blockIdx.x;
  const int l  = (bid & 7) * 64 + (bid >> 3);   // bijective XCD swizzle
  const int nb = l >> 2;
  const int ks = l & 3;
  const int n0 = nb * BN;
  const int ks8 = ks * (KS >> 8);

  const int lane = tid & 63;
  const int wave = tid >> 6;
  const int mb0  = wave * 2;
  const int brow = lane & 31;                  // B col this lane dequants
  const int bco  = lane >> 5;
  const int lxor = ((bco << 1) ^ (((brow >> 3) & 3) << 1));  // reader chunk XOR

  const char* qwb = (const char*)qw;
  const bf16x8* xA0 = PRE ? (xbf + ((mb0    ) * 512 + ks * 128) * 64 + lane) : nullptr;
  const bf16x8* xA1 = PRE ? (xbf + ((mb0 + 1) * 512 + ks * 128) * 64 + lane) : nullptr;

  bf16x8 aA[8], aB[8];
  floatx16 acc00 = {}, acc01 = {}, acc10 = {}, acc11 = {};
  // per-superstep meta registers (rows brow and brow+32)
  float d0, dm0, d1, dm1;
  uintx4 s0r0, s1r0, s2r0, s0r1, s1r1, s2r1;

  // one DMA instruction: 1KB, lanes walk the flat [row][chunk] slot space;
  // source = contiguous 576B row-superblock runs (sub-line XOR permuted)
  auto dmaJ = [&](int j, int sbAbs, int slot) {
    const int i = j * 64 + lane;                 // 0..2367
    const int seg = (i * 56680) >> 21;           // i / 37 (exact on range)
    const int rem = i - seg * 37;
    const int g = (rem < 4) ? rem
                : (rem == 36) ? 0
                : 4 + ((rem - 4) ^ (((seg >> 3) & 3) << 1));
    const char* src = qwb + (size_t)(((n0 + seg) * KB + sbAbs) * 576 + g * 16);
    glds16((const void*)src, (void*)((char*)Qs + slot * (SLOTI * 4) + j * 1024));
  };
  auto stageSB = [&](int sbAbs, int slot) {
    #pragma unroll
    for (int q = 0; q < 9; ++q) dmaJ(q * 4 + wave, sbAbs, slot);
    if (wave == 0) dmaJ(36, sbAbs, slot);
  };

  auto gloadA = [&](int t, bf16x8 (&A)[8]) {
    if constexpr (PRE) {
      const int f = t * 4 * 64;
      #pragma unroll
      for (int kk = 0; kk < 4; ++kk) {
        A[kk]     = gld<bf16x8>(xA0 + f + kk * 64);
        A[4 + kk] = gld<bf16x8>(xA1 + f + kk * 64);
      }
    } else {
      const int kg = ks * KS + t * 64 + bco * 8;
      #pragma unroll
      for (int kk = 0; kk < 4; ++kk) {
        const float* fA = x + (mb0 * 32 + brow) * Kdim + kg + kk * 16;
        const float* fB = x + ((mb0 + 1) * 32 + brow) * Kdim + kg + kk * 16;
        const floatx4 p0 = gld<floatx4>(fA), p1 = gld<floatx4>(fA + 4);
        const floatx4 q0 = gld<floatx4>(fB), q1 = gld<floatx4>(fB + 4);
        U8 ua, ub;
        ua.u[0] = cvtpk(p0.x, p0.y); ua.u[1] = cvtpk(p0.z, p0.w);
        ua.u[2] = cvtpk(p1.x, p1.y); ua.u[3] = cvtpk(p1.z, p1.w);
        ub.u[0] = cvtpk(q0.x, q0.y); ub.u[1] = cvtpk(q0.z, q0.w);
        ub.u[2] = cvtpk(q1.x, q1.y); ub.u[3] = cvtpk(q1.z, q1.w);
        A[kk] = ua.v; A[4 + kk] = ub.v;
      }
    }
  };

  auto loadMeta = [&](int slot) {
    const int b0 = slot * SLOTI + brow * ROWI;
    const int b1 = b0 + 32 * ROWI;
    const uintx4 dd0 = *(const uintx4*)&Qs[b0];
    s0r0 = *(const uintx4*)&Qs[b0 + 4];
    s1r0 = *(const uintx4*)&Qs[b0 + 8];
    s2r0 = *(const uintx4*)&Qs[b0 + 12];
    const uintx4 dd1 = *(const uintx4*)&Qs[b1];
    s0r1 = *(const uintx4*)&Qs[b1 + 4];
    s1r1 = *(const uintx4*)&Qs[b1 + 8];
    s2r1 = *(const uintx4*)&Qs[b1 + 12];
    d0  = __half2float(__ushort_as_half((ushort)((dd0.x & 255u) | ((dd0.y & 255u) << 8))));
    dm0 = __half2float(__ushort_as_half((ushort)((dd0.z & 255u) | ((dd0.w & 255u) << 8))));
    d1  = __half2float(__ushort_as_half((ushort)((dd1.x & 255u) | ((dd1.y & 255u) << 8))));
    dm1 = __half2float(__ushort_as_half((ushort)((dd1.z & 255u) | ((dd1.w & 255u) << 8))));
  };

  // one 64k step: direct dequant from slot -> B frags -> 16 MFMA
  auto mstepD = [&](int T, int slot, const bf16x8 (&A)[8]) {
    const int c = T & 3;
    uint scA0, scB0, mnA0, mnB0, scA1, scB1, mnA1, mnB1;
    if (c == 0) {
      scA0 = s0r0.x & 63u; scB0 = s0r0.y & 63u; mnA0 = s1r0.x & 63u; mnB0 = s1r0.y & 63u;
      scA1 = s0r1.x & 63u; scB1 = s0r1.y & 63u; mnA1 = s1r1.x & 63u; mnB1 = s1r1.y & 63u;
    } else if (c == 1) {
      scA0 = s0r0.z & 63u; scB0 = s0r0.w & 63u; mnA0 = s1r0.z & 63u; mnB0 = s1r0.w & 63u;
      scA1 = s0r1.z & 63u; scB1 = s0r1.w & 63u; mnA1 = s1r1.z & 63u; mnB1 = s1r1.w & 63u;
    } else if (c == 2) {
      scA0 = (s2r0.x & 15u) | ((s0r0.x >> 2) & 48u); scB0 = (s2r0.y & 15u) | ((s0r0.y >> 2) & 48u);
      mnA0 = (s2r0.x >> 4)  | ((s1r0.x >> 2) & 48u); mnB0 = (s2r0.y >> 4)  | ((s1r0.y >> 2) & 48u);
      scA1 = (s2r1.x & 15u) | ((s0r1.x >> 2) & 48u); scB1 = (s2r1.y & 15u) | ((s0r1.y >> 2) & 48u);
      mnA1 = (s2r1.x >> 4)  | ((s1r1.x >> 2) & 48u); mnB1 = (s2r1.y >> 4)  | ((s1r1.y >> 2) & 48u);
    } else {
      scA0 = (s2r0.z & 15u) | ((s0r0.z >> 2) & 48u); scB0 = (s2r0.w & 15u) | ((s0r0.w >> 2) & 48u);
      mnA0 = (s2r0.z >> 4)  | ((s1r0.z >> 2) & 48u); mnB0 = (s2r0.w >> 4)  | ((s1r0.w >> 2) & 48u);
      scA1 = (s2r1.z & 15u) | ((s0r1.z >> 2) & 48u); scB1 = (s2r1.w & 15u) | ((s0r1.w >> 2) & 48u);
      mnA1 = (s2r1.z >> 4)  | ((s1r1.z >> 2) & 48u); mnB1 = (s2r1.w >> 4)  | ((s1r1.w >> 2) & 48u);
    }
    const float dlA0 = d0 * (float)scA0, mlA0 = dm0 * (float)mnA0;
    const float dlB0 = d0 * (float)scB0, mlB0 = dm0 * (float)mnB0;
    const float dlA1 = d1 * (float)scA1, mlA1 = dm1 * (float)mnA1;
    const float dlB1 = d1 * (float)scB1, mlB1 = dm1 * (float)mnB1;
    const int qb0 = slot * SLOTI + brow * ROWI + 16;
    const int qb1 = qb0 + 32 * ROWI;
    #pragma unroll
    for (int kk = 0; kk < 4; ++kk) {
      const int xc = (c * 8 + (kk & 1) * 4) ^ lxor;   // physical chunk (u=0)
      const uintx4 qa0 = *(const uintx4*)&Qs[qb0 + 4 * xc];
      const uintx4 qa1 = *(const uintx4*)&Qs[qb0 + 4 * xc + 4];
      const uintx4 qc0 = *(const uintx4*)&Qs[qb1 + 4 * xc];
      const uintx4 qc1 = *(const uintx4*)&Qs[qb1 + 4 * xc + 4];
      const bool lo = (kk < 2);
      const float dl0 = lo ? dlA0 : dlB0, ml0 = lo ? mlA0 : mlB0;
      const float dl1 = lo ? dlA1 : dlB1, ml1 = lo ? mlA1 : mlB1;
      U8 f0, f1;
      #pragma unroll
      for (int h = 0; h < 2; ++h) {
        const uintx4 va = h ? qa1 : qa0;
        const uintx4 vc = h ? qc1 : qc0;
        const float a0 = fmaf(dl0, (float)(lo ? (va.x & 15u) : (va.x >> 4)), -ml0);
        const float a1 = fmaf(dl0, (float)(lo ? (va.y & 15u) : (va.y >> 4)), -ml0);
        const float a2 = fmaf(dl0, (float)(lo ? (va.z & 15u) : (va.z >> 4)), -ml0);
        const float a3 = fmaf(dl0, (float)(lo ? (va.w & 15u) : (va.w >> 4)), -ml0);
        const float c0 = fmaf(dl1, (float)(lo ? (vc.x & 15u) : (vc.x >> 4)), -ml1);
        const float c1 = fmaf(dl1, (float)(lo ? (vc.y & 15u) : (vc.y >> 4)), -ml1);
        const float c2 = fmaf(dl1, (float)(lo ? (vc.z & 15u) : (vc.z >> 4)), -ml1);
        const float c3 = fmaf(dl1, (float)(lo ? (vc.w & 15u) : (vc.w >> 4)), -ml1);
        f0.u[h * 2]     = cvtpk(a0, a1); f0.u[h * 2 + 1] = cvtpk(a2, a3);
        f1.u[h * 2]     = cvtpk(c0, c1); f1.u[h * 2 + 1] = cvtpk(c2, c3);
      }
      acc00 = __builtin_amdgcn_mfma_f32_32x32x16_bf16(A[kk],     f0.v, acc00, 0, 0, 0);
      acc01 = __builtin_amdgcn_mfma_f32_32x32x16_bf16(A[kk],     f1.v, acc01, 0, 0, 0);
      acc10 = __builtin_amdgcn_mfma_f32_32x32x16_bf16(A[4 + kk], f0.v, acc10, 0, 0, 0);
      acc11 = __builtin_amdgcn_mfma_f32_32x32x16_bf16(A[4 + kk], f1.v, acc11, 0, 0, 0);
    }
  };

  // ---------------- prologue ----------------
  stageSB(ks8, 0);
  gloadA(0, aA);
  gloadA(1, aB);
  if constexpr (PRE) { WAITVM(16); } else { WAITVM(32); }
  __builtin_amdgcn_s_barrier();
  __builtin_amdgcn_sched_barrier(0);

  // -------- 8 supersteps: compute sb S from slot S&1, DMA sb S+1 ----------
  #define SST(S) {                                                           \
    if ((S) < 7) stageSB(ks8 + (S) + 1, ((S) + 1) & 1);                      \
    loadMeta((S) & 1);                                                       \
    mstepD(4*(S) + 0, (S) & 1, aA); if (4*(S) + 2 < NT) gloadA(4*(S) + 2, aA); \
    mstepD(4*(S) + 1, (S) & 1, aB); if (4*(S) + 3 < NT) gloadA(4*(S) + 3, aB); \
    mstepD(4*(S) + 2, (S) & 1, aA); if (4*(S) + 4 < NT) gloadA(4*(S) + 4, aA); \
    mstepD(4*(S) + 3, (S) & 1, aB); if (4*(S) + 5 < NT) gloadA(4*(S) + 5, aB); \
    if ((S) < 7) { if constexpr (PRE) { WAITVM(32); } else { WAITVM(63); } } \
    asm volatile("s_waitcnt lgkmcnt(0)" ::: "memory");                       \
    __builtin_amdgcn_s_barrier();                                            \
    __builtin_amdgcn_sched_barrier(0);                                       \
  }

  SST(0) SST(1) SST(2) SST(3) SST(4) SST(5) SST(6) SST(7)
  #undef SST

  // epilogue: D layout col=lane&31, row=(r&3)+8*(r>>2)+4*(lane>>5)  [m74/m101]
  const int gn0 = n0 + (lane & 31);
  const int gn1 = gn0 + 32;
  const float bv0 = (ks == 0) ? bias[gn0] : 0.0f;
  const float bv1 = (ks == 0) ? bias[gn1] : 0.0f;
  const int mrow = wave * 64 + 4 * (lane >> 5);
  #pragma unroll
  for (int r = 0; r < 16; ++r) {
    const int m = mrow + (r & 3) + 8 * (r >> 2);
    atomicAdd(&out[m * Ndim + gn0], acc00[r] + bv0);
    atomicAdd(&out[m * Ndim + gn1], acc01[r] + bv1);
    atomicAdd(&out[(m + 32) * Ndim + gn0], acc10[r] + bv0);
    atomicAdd(&out[(m + 32) * Ndim + gn1], acc11[r] + bv1);
  }
}

// zero d_out (atomic accumulate target) and optionally pre-tile x -> bf16
// MFMA-fragment layout: xb[(mb*512+kb)*64+lane] = 16B frag slice,
// m = mb*32+(lane&31), k = kb*16+(lane>>5)*8
template<bool DOCVT>
__global__ __launch_bounds__(256)
void prep(const float* __restrict__ x, uintx4* __restrict__ xb,
          floatx4* __restrict__ out)
{
  const int gid = blockIdx.x * 256 + threadIdx.x;
  out[gid * 2]     = floatx4{0.f, 0.f, 0.f, 0.f};
  out[gid * 2 + 1] = floatx4{0.f, 0.f, 0.f, 0.f};
  if (DOCVT) {
    const int lane = gid & 63;
    const int m = ((gid >> 15) * 32) + (lane & 31);
    const int k = (((gid >> 6) & 511) * 16) + (lane >> 5) * 8;
    const floatx4 f0 = gld<floatx4>(x + m * Kdim + k);
    const floatx4 f1 = gld<floatx4>(x + m * Kdim + k + 4);
    uintx4 st;
    st.x = cvtpk(f0.x, f0.y); st.y = cvtpk(f0.z, f0.w);
    st.z = cvtpk(f1.x, f1.y); st.w = cvtpk(f1.z, f1.w);
    xb[gid] = st;
  }
}

extern "C" void kernel_launch(void* const* d_in, const int* in_sizes, int n_in,
                              void* d_out, int out_size, void* d_ws, size_t ws_size,
                              hipStream_t stream) {
  (void)in_sizes; (void)n_in; (void)out_size;
  const float* x    = (const float*)d_in[0];
  const int*   qw   = (const int*)d_in[1];
  const float* bias = (const float*)d_in[2];
  float* out = (float*)d_out;

  const size_t need = (size_t)Mdim * Kdim * 2;   // 4 MB bf16 fragment tiles
  if (ws_size >= need) {
    prep<true><<<1024, 256, 0, stream>>>(x, (uintx4*)d_ws, (floatx4*)out);
    q4k_gemm<true><<<512, 256, 0, stream>>>(x, (const bf16x8*)d_ws, qw, bias, out);
  } else {
    prep<false><<<1024, 256, 0, stream>>>(x, nullptr, (floatx4*)out);
    q4k_gemm<false><<<512, 256, 0, stream>>>(x, nullptr, qw, bias, out);
  }
}